// Round 13
// baseline (21.543 us; speedup 1.0000x reference)
//
#include <hip/hip_runtime.h>
#include <hip/hip_bf16.h>

// BatchAllTripletLoss, B=512, E=128, labels in [0,64), MARGIN=1.0, EPS=1e-16.
// K1 dist_mfma:  D[i][j] = max(n_i + n_j - 2 e_i.e_j, 0) via bf16 MFMA +
//                positive-list meta for its 2 anchors (proven R11). Block 0
//                zeroes the 8 u64 accumulators AND the arrival counter
//                (K1 completes before K2 in stream order -> visible).
// K2 hinge_pass: 256 blocks, 2 anchors each (proven R11) + fused finalize:
//                per-block partials -> fixed-point u64 atomicAdd (4-way
//                spread, order-independent = deterministic), __threadfence,
//                arrival counter; EXACT last block (old == 255, ctr zeroed
//                by K1 each launch) reads 8 u64 via RMW, writes out[0].

#define BSZ 512
#define EDIM 128
#define TS 32
#define NPOS 64   // meta stride: [np, plist[0..62]]
#define FPSCALE 1048576.0  // 2^20

typedef __attribute__((ext_vector_type(8))) short short8;
typedef __attribute__((ext_vector_type(4))) float f32x4;

__device__ __forceinline__ unsigned short f2bf(float f) {
    __hip_bfloat16 h = __float2bfloat16(f);
    return *reinterpret_cast<unsigned short*>(&h);
}

__global__ __launch_bounds__(256) void dist_mfma(
    const float* __restrict__ embs,
    const int* __restrict__ labels,
    float* __restrict__ D,
    int* __restrict__ meta,
    unsigned long long* __restrict__ accs,
    unsigned int* __restrict__ ctr)
{
    __shared__ unsigned short Abf[TS][136];
    __shared__ unsigned short Bbf[TS][136];   // holds -2*b (exact scale)
    __shared__ float nA[TS], nB[TS];
    __shared__ int   lab[BSZ];
    __shared__ unsigned long long m0sh[8], m1sh[8];

    const int tid = threadIdx.x;
    const int bi = blockIdx.x >> 4;
    const int bj = blockIdx.x & 15;
    const int I = bi * TS, J = bj * TS;
    const int wv = tid >> 6, lane = tid & 63;
    const int a0 = blockIdx.x * 2, a1 = a0 + 1;

    if (blockIdx.x == 0) {                 // zero finalize state for K2
        if (tid < 8) accs[tid] = 0ull;
        if (tid == 8) *ctr = 0u;
    }

    const float4* E4 = reinterpret_cast<const float4*>(embs);

    // ---- stage fp32 -> bf16 LDS + exact fp32 norms + labels ----
#pragma unroll
    for (int q = 0; q < 4; ++q) {
        int idx = tid + 256 * q;
        int r   = idx >> 5;
        int k4  = idx & 31;

        float4 va = E4[(size_t)(I + r) * (EDIM / 4) + k4];
        float sa = va.x * va.x + va.y * va.y + va.z * va.z + va.w * va.w;
        sa += __shfl_xor(sa, 1); sa += __shfl_xor(sa, 2); sa += __shfl_xor(sa, 4);
        sa += __shfl_xor(sa, 8); sa += __shfl_xor(sa, 16);
        if ((tid & 31) == 0) nA[r] = sa;
        ushort4 ua = { f2bf(va.x), f2bf(va.y), f2bf(va.z), f2bf(va.w) };
        *reinterpret_cast<ushort4*>(&Abf[r][k4 * 4]) = ua;

        float4 vb = E4[(size_t)(J + r) * (EDIM / 4) + k4];
        float sb = vb.x * vb.x + vb.y * vb.y + vb.z * vb.z + vb.w * vb.w;
        sb += __shfl_xor(sb, 1); sb += __shfl_xor(sb, 2); sb += __shfl_xor(sb, 4);
        sb += __shfl_xor(sb, 8); sb += __shfl_xor(sb, 16);
        if ((tid & 31) == 0) nB[r] = sb;
        ushort4 ub = { f2bf(-2.f * vb.x), f2bf(-2.f * vb.y),
                       f2bf(-2.f * vb.z), f2bf(-2.f * vb.w) };
        *reinterpret_cast<ushort4*>(&Bbf[r][k4 * 4]) = ub;
    }
    lab[tid]       = labels[tid];
    lab[tid + 256] = labels[tid + 256];
    __syncthreads();

    // ---- ballots for this block's 2 meta-anchors ----
    const int la0 = lab[a0], la1 = lab[a1];
#pragma unroll
    for (int c = 0; c < 2; ++c) {
        int j = c * 256 + tid;
        unsigned long long m0 = __ballot(lab[j] == la0 && j != a0);
        unsigned long long m1 = __ballot(lab[j] == la1 && j != a1);
        if (lane == 0) { m0sh[c * 4 + wv] = m0; m1sh[c * 4 + wv] = m1; }
    }
    __syncthreads();

    // ---- MFMA quadrant (wv): acc init = nA[row]+nB[col] ----
    const int qi = wv >> 1, qj = wv & 1;
    const int l15 = lane & 15, lk = lane >> 4;

    f32x4 acc;
#pragma unroll
    for (int reg = 0; reg < 4; ++reg)
        acc[reg] = nA[qi * 16 + lk * 4 + reg] + nB[qj * 16 + l15];

    const unsigned short* arow = &Abf[qi * 16 + l15][0];
    const unsigned short* brow = &Bbf[qj * 16 + l15][0];
#pragma unroll
    for (int ks = 0; ks < 4; ++ks) {
        short8 af = *reinterpret_cast<const short8*>(arow + ks * 32 + lk * 8);
        short8 bf = *reinterpret_cast<const short8*>(brow + ks * 32 + lk * 8);
        acc = __builtin_amdgcn_mfma_f32_16x16x32_bf16(af, bf, acc, 0, 0, 0);
    }
#pragma unroll
    for (int reg = 0; reg < 4; ++reg) {
        int row = I + qi * 16 + lk * 4 + reg;
        int col = J + qj * 16 + l15;
        D[(size_t)row * BSZ + col] = fmaxf(acc[reg], 0.f);
    }

    // ---- meta compaction (rank via popcount) ----
    int np0 = 0, np1 = 0;
#pragma unroll
    for (int m = 0; m < 8; ++m) { np0 += __popcll(m0sh[m]); np1 += __popcll(m1sh[m]); }
    if (np0 > NPOS - 1) np0 = NPOS - 1;
    if (np1 > NPOS - 1) np1 = NPOS - 1;

#pragma unroll
    for (int c = 0; c < 2; ++c) {
        int j = c * 256 + tid;
        if (lab[j] == la0 && j != a0) {
            int mi = c * 4 + wv, off = 0;
            for (int m = 0; m < mi; ++m) off += __popcll(m0sh[m]);
            off += __popcll(m0sh[mi] & ((1ull << lane) - 1ull));
            if (off < NPOS - 1) meta[a0 * NPOS + 1 + off] = j;
        }
        if (lab[j] == la1 && j != a1) {
            int mi = c * 4 + wv, off = 0;
            for (int m = 0; m < mi; ++m) off += __popcll(m1sh[m]);
            off += __popcll(m1sh[mi] & ((1ull << lane) - 1ull));
            if (off < NPOS - 1) meta[a1 * NPOS + 1 + off] = j;
        }
    }
    if (tid == 0) { meta[a0 * NPOS] = np0; meta[a1 * NPOS] = np1; }
}

__global__ __launch_bounds__(256) void hinge_pass(
    const float* __restrict__ D,
    const int* __restrict__ labels,
    const int* __restrict__ meta,
    unsigned long long* __restrict__ accs,  // [0..3]=sum lanes, [4..7]=cnt lanes
    unsigned int* __restrict__ ctr,
    float* __restrict__ out)
{
    __shared__ float pd0[NPOS], pd1[NPOS];
    __shared__ int   npsh[2];
    __shared__ float wsum[4];
    __shared__ int   wcnt[4];
    __shared__ int   isLast;

    const int tid = threadIdx.x;
    const int wv = tid >> 6, lane = tid & 63;
    const int b = blockIdx.x, a0 = 2 * b, a1 = a0 + 1;

    // waves 0/1: gather positive distances via meta
    if (wv == 0) {
        int v = meta[a0 * NPOS + lane];
        int np = __shfl(v, 0);
        if (lane == 0) npsh[0] = np;
        if (lane >= 1 && lane <= np) pd0[lane - 1] = D[(size_t)a0 * BSZ + v];
    } else if (wv == 1) {
        int v = meta[a1 * NPOS + lane];
        int np = __shfl(v, 0);
        if (lane == 0) npsh[1] = np;
        if (lane >= 1 && lane <= np) pd1[lane - 1] = D[(size_t)a1 * BSZ + v];
    }

    const int la0 = labels[a0], la1 = labels[a1];
    int2   ln = reinterpret_cast<const int2*>(labels)[tid];
    float2 r0 = reinterpret_cast<const float2*>(D + (size_t)a0 * BSZ)[tid];
    float2 r1 = reinterpret_cast<const float2*>(D + (size_t)a1 * BSZ)[tid];
    __syncthreads();

    const int np0 = npsh[0], np1 = npsh[1];
    float s = 0.f;
    int   c = 0;
    if (ln.x != la0) for (int i = 0; i < np0; ++i) { float t = fmaxf(pd0[i] - r0.x + 1.0f, 0.f); s += t; c += (t > 1e-16f); }
    if (ln.y != la0) for (int i = 0; i < np0; ++i) { float t = fmaxf(pd0[i] - r0.y + 1.0f, 0.f); s += t; c += (t > 1e-16f); }
    if (ln.x != la1) for (int i = 0; i < np1; ++i) { float t = fmaxf(pd1[i] - r1.x + 1.0f, 0.f); s += t; c += (t > 1e-16f); }
    if (ln.y != la1) for (int i = 0; i < np1; ++i) { float t = fmaxf(pd1[i] - r1.y + 1.0f, 0.f); s += t; c += (t > 1e-16f); }

#pragma unroll
    for (int off = 32; off; off >>= 1) {
        s += __shfl_down(s, off);
        c += __shfl_down(c, off);
    }
    if (lane == 0) { wsum[wv] = s; wcnt[wv] = c; }
    __syncthreads();

    // ---- fused finalize: fixed-point u64 atomics + exact arrival count ----
    if (tid == 0) {
        double Sb = (double)(wsum[0] + wsum[1] + wsum[2] + wsum[3]);
        unsigned long long qs = (unsigned long long)llrint(Sb * FPSCALE);
        unsigned long long qc = (unsigned long long)(wcnt[0] + wcnt[1] + wcnt[2] + wcnt[3]);
        atomicAdd(&accs[b & 3], qs);
        atomicAdd(&accs[4 + (b & 3)], qc);
        __threadfence();                          // release: sum-adds before arrival
        unsigned int old = atomicAdd(ctr, 1u);
        isLast = (old == 255u) ? 1 : 0;           // exact: ctr zeroed by K1 each launch
    }
    __syncthreads();

    if (isLast && tid == 0) {
        unsigned long long S = 0ull, C = 0ull;
#pragma unroll
        for (int i = 0; i < 4; ++i) {
            S += atomicAdd(&accs[i], 0ull);       // RMW read at coherence point
            C += atomicAdd(&accs[4 + i], 0ull);
        }
        out[0] = (float)(((double)S / FPSCALE) / ((double)C + 1e-16));
    }
}

extern "C" void kernel_launch(void* const* d_in, const int* in_sizes, int n_in,
                              void* d_out, int out_size, void* d_ws, size_t ws_size,
                              hipStream_t stream)
{
    const float* embs   = reinterpret_cast<const float*>(d_in[0]);
    const int*   labels = reinterpret_cast<const int*>(d_in[1]);
    float*       out    = reinterpret_cast<float*>(d_out);

    float* D    = reinterpret_cast<float*>(d_ws);                 // 1 MB
    int*   meta = reinterpret_cast<int*>(D + (size_t)BSZ * BSZ);  // 128 KB
    unsigned long long* accs = reinterpret_cast<unsigned long long*>(meta + BSZ * NPOS); // 64 B
    unsigned int* ctr = reinterpret_cast<unsigned int*>(accs + 8);

    dist_mfma<<<256, 256, 0, stream>>>(embs, labels, D, meta, accs, ctr);
    hinge_pass<<<256, 256, 0, stream>>>(D, labels, meta, accs, ctr, out);
}

// Round 14
// 15.647 us; speedup vs baseline: 1.3768x; 1.3768x over previous
//
#include <hip/hip_runtime.h>
#include <hip/hip_bf16.h>

// BatchAllTripletLoss, B=512, E=128, labels in [0,64), MARGIN=1.0, EPS=1e-16.
// K1 dist_mfma_sym: D symmetric -> only 136 upper-triangle 32x32 tiles
//                   (16x17/2). bf16 MFMA tile (proven R10 math). Off-diag
//                   blocks also store the mirrored tile as per-lane float4
//                   (4 acc regs = 4 consecutive cols of mirror row).
//                   Diagonal blocks store direct only (no duplicate writes).
// K2 triplet_pass:  unchanged from proven R10 (512 blocks, ballots, hinge).
// K3 finalize:      unchanged from proven R10.
// No atomics anywhere -> deterministic.

#define BSZ 512
#define EDIM 128
#define TS 32
#define NPOSMAX 96

typedef __attribute__((ext_vector_type(8))) short short8;
typedef __attribute__((ext_vector_type(4))) float f32x4;

__device__ __forceinline__ unsigned short f2bf(float f) {
    __hip_bfloat16 h = __float2bfloat16(f);
    return *reinterpret_cast<unsigned short*>(&h);
}

__global__ __launch_bounds__(256) void dist_mfma_sym(
    const float* __restrict__ embs,
    float* __restrict__ D)
{
    __shared__ unsigned short Abf[TS][136];
    __shared__ unsigned short Bbf[TS][136];   // holds -2*b (exact scale)
    __shared__ float nA[TS], nB[TS];

    const int tid = threadIdx.x;

    // triangular decode: block t -> (bi, bj), bi <= bj
    int t = blockIdx.x, bi = 0;
    while (t >= 16 - bi) { t -= 16 - bi; ++bi; }
    const int bj = bi + t;
    const int I = bi * TS, J = bj * TS;
    const int wv = tid >> 6, lane = tid & 63;

    const float4* E4 = reinterpret_cast<const float4*>(embs);

    // ---- stage fp32 -> bf16 LDS + exact fp32 norms ----
#pragma unroll
    for (int q = 0; q < 4; ++q) {
        int idx = tid + 256 * q;
        int r   = idx >> 5;
        int k4  = idx & 31;

        float4 va = E4[(size_t)(I + r) * (EDIM / 4) + k4];
        float sa = va.x * va.x + va.y * va.y + va.z * va.z + va.w * va.w;
        sa += __shfl_xor(sa, 1); sa += __shfl_xor(sa, 2); sa += __shfl_xor(sa, 4);
        sa += __shfl_xor(sa, 8); sa += __shfl_xor(sa, 16);
        if ((tid & 31) == 0) nA[r] = sa;
        ushort4 ua = { f2bf(va.x), f2bf(va.y), f2bf(va.z), f2bf(va.w) };
        *reinterpret_cast<ushort4*>(&Abf[r][k4 * 4]) = ua;

        float4 vb = E4[(size_t)(J + r) * (EDIM / 4) + k4];
        float sb = vb.x * vb.x + vb.y * vb.y + vb.z * vb.z + vb.w * vb.w;
        sb += __shfl_xor(sb, 1); sb += __shfl_xor(sb, 2); sb += __shfl_xor(sb, 4);
        sb += __shfl_xor(sb, 8); sb += __shfl_xor(sb, 16);
        if ((tid & 31) == 0) nB[r] = sb;
        ushort4 ub = { f2bf(-2.f * vb.x), f2bf(-2.f * vb.y),
                       f2bf(-2.f * vb.z), f2bf(-2.f * vb.w) };
        *reinterpret_cast<ushort4*>(&Bbf[r][k4 * 4]) = ub;
    }
    __syncthreads();

    // ---- MFMA quadrant (wv): acc init = nA[row]+nB[col] ----
    const int qi = wv >> 1, qj = wv & 1;
    const int l15 = lane & 15, lk = lane >> 4;

    f32x4 acc;
#pragma unroll
    for (int reg = 0; reg < 4; ++reg)
        acc[reg] = nA[qi * 16 + lk * 4 + reg] + nB[qj * 16 + l15];

    const unsigned short* arow = &Abf[qi * 16 + l15][0];
    const unsigned short* brow = &Bbf[qj * 16 + l15][0];
#pragma unroll
    for (int ks = 0; ks < 4; ++ks) {
        short8 af = *reinterpret_cast<const short8*>(arow + ks * 32 + lk * 8);
        short8 bf = *reinterpret_cast<const short8*>(brow + ks * 32 + lk * 8);
        acc = __builtin_amdgcn_mfma_f32_16x16x32_bf16(af, bf, acc, 0, 0, 0);
    }

    // clamp
#pragma unroll
    for (int reg = 0; reg < 4; ++reg) acc[reg] = fmaxf(acc[reg], 0.f);

    // ---- direct store (coalesced-ish) ----
#pragma unroll
    for (int reg = 0; reg < 4; ++reg) {
        int row = I + qi * 16 + lk * 4 + reg;
        int col = J + qj * 16 + l15;
        D[(size_t)row * BSZ + col] = acc[reg];
    }

    // ---- mirror store for off-diagonal tiles: per-lane float4 ----
    if (bi != bj) {
        int mrow = J + qj * 16 + l15;
        int mcol = I + qi * 16 + lk * 4;
        float4 m = make_float4(acc[0], acc[1], acc[2], acc[3]);
        *reinterpret_cast<float4*>(&D[(size_t)mrow * BSZ + mcol]) = m;
    }
}

__global__ __launch_bounds__(256) void triplet_pass(
    const float* __restrict__ D,
    const int* __restrict__ labels,
    float* __restrict__ sums,
    float* __restrict__ cnts)
{
    __shared__ int   lab[BSZ];
    __shared__ float d[BSZ];
    __shared__ unsigned long long masks[8];
    __shared__ int   plist[NPOSMAX];
    __shared__ float wsum[4];
    __shared__ int   wcnt[4];

    const int a = blockIdx.x, tid = threadIdx.x;
    const int wv = tid >> 6, lane = tid & 63;

    lab[tid]       = labels[tid];
    lab[tid + 256] = labels[tid + 256];
    float2 dv = reinterpret_cast<const float2*>(D + (size_t)a * BSZ)[tid];
    d[tid * 2]     = dv.x;
    d[tid * 2 + 1] = dv.y;
    __syncthreads();

    const int la = lab[a];

#pragma unroll
    for (int c = 0; c < 2; ++c) {
        int j = c * 256 + tid;
        unsigned long long m = __ballot(lab[j] == la && j != a);
        if (lane == 0) masks[c * 4 + wv] = m;
    }
    __syncthreads();

    int np = 0;
#pragma unroll
    for (int m = 0; m < 8; ++m) np += __popcll(masks[m]);
    if (np > NPOSMAX) np = NPOSMAX;

#pragma unroll
    for (int c = 0; c < 2; ++c) {
        int j = c * 256 + tid;
        if (lab[j] == la && j != a) {
            int mi = c * 4 + wv, off = 0;
            for (int m = 0; m < mi; ++m) off += __popcll(masks[m]);
            off += __popcll(masks[mi] & ((1ull << lane) - 1ull));
            if (off < NPOSMAX) plist[off] = j;
        }
    }
    __syncthreads();

    float s = 0.f;
    int   cnt = 0;
#pragma unroll
    for (int c = 0; c < 2; ++c) {
        int n = c * 256 + tid;
        if (lab[n] != la) {
            float dn = d[n];
            for (int i = 0; i < np; ++i) {
                float t = fmaxf(d[plist[i]] - dn + 1.0f, 0.f);
                s += t;
                cnt += (t > 1e-16f) ? 1 : 0;
            }
        }
    }

#pragma unroll
    for (int off = 32; off; off >>= 1) {
        s   += __shfl_down(s, off);
        cnt += __shfl_down(cnt, off);
    }
    if (lane == 0) { wsum[wv] = s; wcnt[wv] = cnt; }
    __syncthreads();
    if (tid == 0) {
        sums[a] = wsum[0] + wsum[1] + wsum[2] + wsum[3];
        cnts[a] = (float)(wcnt[0] + wcnt[1] + wcnt[2] + wcnt[3]);
    }
}

__global__ __launch_bounds__(512) void finalize(
    const float* __restrict__ sums,
    const float* __restrict__ cnts,
    float* __restrict__ out)
{
    __shared__ float wsum[8], wcnt[8];
    const int tid = threadIdx.x;
    float s = sums[tid];
    float c = cnts[tid];
#pragma unroll
    for (int off = 32; off; off >>= 1) {
        s += __shfl_down(s, off);
        c += __shfl_down(c, off);
    }
    const int wv = tid >> 6, lane = tid & 63;
    if (lane == 0) { wsum[wv] = s; wcnt[wv] = c; }
    __syncthreads();
    if (tid == 0) {
        float S = 0.f, C = 0.f;
#pragma unroll
        for (int w = 0; w < 8; ++w) { S += wsum[w]; C += wcnt[w]; }
        out[0] = S / (C + 1e-16f);
    }
}

extern "C" void kernel_launch(void* const* d_in, const int* in_sizes, int n_in,
                              void* d_out, int out_size, void* d_ws, size_t ws_size,
                              hipStream_t stream)
{
    const float* embs   = reinterpret_cast<const float*>(d_in[0]);
    const int*   labels = reinterpret_cast<const int*>(d_in[1]);
    float*       out    = reinterpret_cast<float*>(d_out);

    float* D    = reinterpret_cast<float*>(d_ws);                 // 1 MB
    float* sums = D + (size_t)BSZ * BSZ;                          // 2 KB
    float* cnts = sums + BSZ;                                     // 2 KB

    dist_mfma_sym<<<136, 256, 0, stream>>>(embs, D);
    triplet_pass<<<BSZ, 256, 0, stream>>>(D, labels, sums, cnts);
    finalize<<<1, 512, 0, stream>>>(sums, cnts, out);
}